// Round 9
// baseline (447.137 us; speedup 1.0000x reference)
//
#include <hip/hip_runtime.h>
#include <hip/hip_bf16.h>
#include <math.h>

// Problem constants
#define R_   8192    // B*S rows
#define DM   1024    // d_model
#define DFF  4096    // d_ff
#define NP   64      // n_patterns
#define KN   8       // K neurons

typedef __bf16 bf16x8 __attribute__((ext_vector_type(8)));
typedef float  f32x4  __attribute__((ext_vector_type(4)));
typedef float  f32x16 __attribute__((ext_vector_type(16)));

__device__ __forceinline__ unsigned short f2bf(float f) {
  union { float f; unsigned u; } v; v.f = f;
  unsigned u = v.u;
  return (unsigned short)((u + 0x7FFFu + ((u >> 16) & 1u)) >> 16);
}

__device__ __forceinline__ float dot4(const float4 a, const float4 b) {
  return a.x * b.x + a.y * b.y + a.z * b.z + a.w * b.w;
}

__device__ __forceinline__ void fma4(float4& a, float w, const float4 s) {
  a.x += w * s.x; a.y += w * s.y; a.z += w * s.z; a.w += w * s.w;
}

// ---------------------------------------------------------------- f32 -> bf16
__global__ __launch_bounds__(256) void cvt_bf16_kernel(
    const float* __restrict__ in, unsigned short* __restrict__ out, int n8) {
  int i = blockIdx.x * 256 + threadIdx.x;
  if (i >= n8) return;
  const float4* p = (const float4*)in + (size_t)i * 2;
  float4 a = p[0], b = p[1];
  uint4 r;
  r.x = (unsigned)f2bf(a.x) | ((unsigned)f2bf(a.y) << 16);
  r.y = (unsigned)f2bf(a.z) | ((unsigned)f2bf(a.w) << 16);
  r.z = (unsigned)f2bf(b.x) | ((unsigned)f2bf(b.y) << 16);
  r.w = (unsigned)f2bf(b.z) | ((unsigned)f2bf(b.w) << 16);
  ((uint4*)out)[i] = r;
}

// -------------------------------------------------------------- v materialize
__global__ __launch_bounds__(256) void vcomp_kernel(
    const float* __restrict__ sn,    // [R_][8][1024]
    const float* __restrict__ tw,    // [R_][8]
    float* __restrict__ v)           // [R_][1024]
{
  const int r = blockIdx.x;
  const int t = threadIdx.x;
  float w[KN];
#pragma unroll
  for (int k = 0; k < KN; ++k) w[k] = tw[(size_t)r * KN + k];
  const float* base = sn + (size_t)r * (KN * DM) + t * 4;
  float4 a = {0.f, 0.f, 0.f, 0.f};
#pragma unroll
  for (int k = 0; k < KN; ++k) fma4(a, w[k], *(const float4*)(base + k * DM));
  *(float4*)(v + (size_t)r * DM + t * 4) = a;
}

// ------------------------------------------------- pattern scores/topk/softmax
__global__ __launch_bounds__(256, 2) void score_kernel(
    const float* __restrict__ v,     // [R_][1024]
    const float* __restrict__ pq,    // [64][1024]
    int*   __restrict__ out_idx,     // [R_][4]
    float* __restrict__ out_w)       // [R_][4]
{
  const int lane = threadIdx.x & 63;
  const int wave = threadIdx.x >> 6;
  const int pos0 = (blockIdx.x * 4 + wave) * 4;

  float4 vr[4][4];
#pragma unroll
  for (int p = 0; p < 4; ++p) {
    const float4* s = (const float4*)(v + (size_t)(pos0 + p) * DM + lane * 16);
    vr[p][0] = s[0]; vr[p][1] = s[1]; vr[p][2] = s[2]; vr[p][3] = s[3];
  }

  float sreg[4];
#pragma unroll 1
  for (int pat = 0; pat < NP; ++pat) {
    const float4* q = (const float4*)(pq + pat * DM + lane * 16);
    const float4 q0 = q[0], q1 = q[1], q2 = q[2], q3 = q[3];
    float part[4];
#pragma unroll
    for (int p = 0; p < 4; ++p)
      part[p] = dot4(q0, vr[p][0]) + dot4(q1, vr[p][1]) +
                dot4(q2, vr[p][2]) + dot4(q3, vr[p][3]);
#pragma unroll
    for (int off = 32; off >= 1; off >>= 1) {
#pragma unroll
      for (int p = 0; p < 4; ++p)
        part[p] += __shfl_xor(part[p], off, 64);
    }
    if (lane == pat) {
#pragma unroll
      for (int p = 0; p < 4; ++p) sreg[p] = part[p] * 0.03125f; // /sqrt(1024)
    }
  }

#pragma unroll
  for (int p = 0; p < 4; ++p) {
    float cur = sreg[p];
    float m0, m1, m2, m3; int i0, i1, i2, i3;
#define ARGMAX_STEP(MV, MI)                                   \
    {                                                         \
      float bv = cur; int bi = lane;                          \
      _Pragma("unroll")                                       \
      for (int off = 32; off >= 1; off >>= 1) {               \
        float ov = __shfl_xor(bv, off, 64);                   \
        int   oi = __shfl_xor(bi, off, 64);                   \
        if (ov > bv || (ov == bv && oi < bi)) { bv = ov; bi = oi; } \
      }                                                       \
      MV = bv; MI = bi;                                       \
      if (lane == bi) cur = -3.0e38f;                         \
    }
    ARGMAX_STEP(m0, i0) ARGMAX_STEP(m1, i1) ARGMAX_STEP(m2, i2) ARGMAX_STEP(m3, i3)
#undef ARGMAX_STEP
    const float e1 = __expf(m1 - m0), e2 = __expf(m2 - m0), e3 = __expf(m3 - m0);
    const float inv = 1.f / (1.f + e1 + e2 + e3);
    if (lane < 4) {
      const int r = pos0 + p;
      const int myi = (lane == 0) ? i0 : (lane == 1) ? i1 : (lane == 2) ? i2 : i3;
      const float mye = (lane == 0) ? 1.f : (lane == 1) ? e1 : (lane == 2) ? e2 : e3;
      out_idx[r * 4 + lane] = myi;
      out_w[r * 4 + lane] = mye * inv;
    }
  }
}

// ------------------------------------------------------------ GEMM machinery
__device__ __forceinline__ void gll16(const void* g, void* l) {
  __builtin_amdgcn_global_load_lds(
      (const __attribute__((address_space(1))) unsigned int*)g,
      (__attribute__((address_space(3))) unsigned int*)l, 16, 0, 0);
}

// 32x32x16 MFMA GEMMs, R2-proven single-buffer 2-barrier loop, BK=32.
// LDS row = 64B (32 bf16) = 4 x 16B slots; element slot s stored at
// s ^ ((row>>1)&3)  [R4-verified 2-way spread = free].
//   writer (linear gll16 dest): thread t fetches global slot (t&3)^((t>>3)&3)
//   reader: frag slot s = ks*2 + (lane>>5), read at s ^ ((lane>>1)&3)
// A/B frag (32x32x16): row = lane&31, k = (lane>>5)*8 + e  (4 VGPR = 8 bf16).
// C/D: col = lane&31, row = (reg&3) + 8*(reg>>2) + 4*(lane>>5)  [m74/m101].

// ---- GEMM1: H = gelu_gate(xb[8192][1024] @ uwb[4096][1024]^T)
// block 256x128, 4 waves (2x2), wave-tile 128x64 = 4x2 of 32x32. grid 32x32.
__global__ __launch_bounds__(256, 2) void gemm1_kernel(
    const unsigned short* __restrict__ A,
    const unsigned short* __restrict__ Bm,
    const float* __restrict__ bias,
    const int*   __restrict__ pidx,
    const float* __restrict__ pwt,
    const float* __restrict__ gates,
    unsigned short* __restrict__ H)
{
  constexpr int K_ = 1024;
  __shared__ __align__(16) char smem[24576];   // A 16KB + B 8KB
  const int tid = threadIdx.x, lane = tid & 63, wid = tid >> 6;
  const int wr = wid >> 1, wc = wid & 1;

  // XCD chunking, weights(B)-resident: consecutive swzb share bcol
  const int cpx = gridDim.x >> 3;
  const int swzb = ((int)blockIdx.x & 7) * cpx + ((int)blockIdx.x >> 3);
  const int brow = swzb & 31, bcol = swzb >> 5;

  const unsigned short* Ab = A  + (size_t)brow * 256 * K_;
  const unsigned short* Bb = Bm + (size_t)bcol * 128 * K_;

  const int slotg = ((tid & 3) ^ ((tid >> 3) & 3)) * 8;  // element offset
  const int srow  = tid >> 2;                            // 0..63
  const int rA    = (lane & 31) * 64;
  const int swk0  = (((lane >> 5))     ^ ((lane >> 1) & 3)) * 16;
  const int swk1  = ((2 + (lane >> 5)) ^ ((lane >> 1) & 3)) * 16;

  f32x16 acc[4][2];
#pragma unroll
  for (int m = 0; m < 4; ++m)
#pragma unroll
    for (int n = 0; n < 2; ++n)
#pragma unroll
      for (int e = 0; e < 16; ++e) acc[m][n][e] = 0.f;

#pragma unroll 1
  for (int k0 = 0; k0 < K_; k0 += 32) {
    if (k0) __syncthreads();
#pragma unroll
    for (int c = 0; c < 4; ++c)
      gll16(Ab + (size_t)(c * 64 + srow) * K_ + k0 + slotg,
            smem + c * 4096 + wid * 1024);
#pragma unroll
    for (int c = 0; c < 2; ++c)
      gll16(Bb + (size_t)(c * 64 + srow) * K_ + k0 + slotg,
            smem + 16384 + c * 4096 + wid * 1024);
    __syncthreads();   // compiler drains vmcnt before barrier

#pragma unroll
    for (int ks = 0; ks < 2; ++ks) {
      const int sw = ks ? swk1 : swk0;
      const char* pa = smem + wr * 8192 + rA + sw;
      const char* pb = smem + 16384 + wc * 4096 + rA + sw;
      bf16x8 af[4], bf[2];
#pragma unroll
      for (int m = 0; m < 4; ++m) af[m] = *(const bf16x8*)(pa + m * 2048);
#pragma unroll
      for (int n = 0; n < 2; ++n) bf[n] = *(const bf16x8*)(pb + n * 2048);
#pragma unroll
      for (int m = 0; m < 4; ++m)
#pragma unroll
        for (int n = 0; n < 2; ++n)
          acc[m][n] = __builtin_amdgcn_mfma_f32_32x32x16_bf16(
              af[m], bf[n], acc[m][n], 0, 0, 0);
    }
  }

  // epilogue: C/D col = lane&31, row = (reg&3)+8*(reg>>2)+4*(lane>>5)
  const int crow0 = brow * 256 + wr * 128;
  const int ccol0 = bcol * 128 + wc * 64 + (lane & 31);
  const int rhalf = (lane >> 5) * 4;
  const float ub0 = bias[ccol0];
  const float ub1 = bias[ccol0 + 32];
#pragma unroll
  for (int m = 0; m < 4; ++m) {
#pragma unroll
    for (int reg = 0; reg < 16; ++reg) {
      const int row = crow0 + m * 32 + (reg & 3) + 8 * (reg >> 2) + rhalf;
      const int4   iq = *(const int4*)(pidx + (size_t)row * 4);
      const float4 wq = *(const float4*)(pwt + (size_t)row * 4);
      const float* g0 = gates + (size_t)iq.x * DFF;
      const float* g1 = gates + (size_t)iq.y * DFF;
      const float* g2 = gates + (size_t)iq.z * DFF;
      const float* g3 = gates + (size_t)iq.w * DFF;
#pragma unroll
      for (int n = 0; n < 2; ++n) {
        const int col = ccol0 + n * 32;
        const float g = wq.x * g0[col] + wq.y * g1[col] +
                        wq.z * g2[col] + wq.w * g3[col];
        const float u   = acc[m][n][reg] + (n ? ub1 : ub0);
        const float val = u * (1.f / (1.f + __expf(-g)));
        const float h   = 0.5f * val * (1.f + erff(val * 0.70710678118654752f));
        H[(size_t)row * DFF + col] = f2bf(h);
      }
    }
  }
}

// ---- GEMM2: out = H[8192][4096] @ dwb[1024][4096]^T + dnb
// block 128x128, 4 waves (2x2), wave-tile 64x64 = 2x2 of 32x32. grid 64x8.
__global__ __launch_bounds__(256, 2) void gemm2_kernel(
    const unsigned short* __restrict__ A,
    const unsigned short* __restrict__ Bm,
    const float* __restrict__ bias,
    float* __restrict__ O)
{
  constexpr int K_ = 4096;
  __shared__ __align__(16) char smem[16384];   // A 8KB + B 8KB
  const int tid = threadIdx.x, lane = tid & 63, wid = tid >> 6;
  const int wr = wid >> 1, wc = wid & 1;

  const int cpx = gridDim.x >> 3;
  const int swzb = ((int)blockIdx.x & 7) * cpx + ((int)blockIdx.x >> 3);
  const int brow = swzb & 63, bcol = swzb >> 6;   // B-panel resident per chunk

  const unsigned short* Ab = A  + (size_t)brow * 128 * K_;
  const unsigned short* Bb = Bm + (size_t)bcol * 128 * K_;

  const int slotg = ((tid & 3) ^ ((tid >> 3) & 3)) * 8;
  const int srow  = tid >> 2;
  const int rA    = (lane & 31) * 64;
  const int swk0  = (((lane >> 5))     ^ ((lane >> 1) & 3)) * 16;
  const int swk1  = ((2 + (lane >> 5)) ^ ((lane >> 1) & 3)) * 16;

  f32x16 acc[2][2];
#pragma unroll
  for (int m = 0; m < 2; ++m)
#pragma unroll
    for (int n = 0; n < 2; ++n)
#pragma unroll
      for (int e = 0; e < 16; ++e) acc[m][n][e] = 0.f;

#pragma unroll 1
  for (int k0 = 0; k0 < K_; k0 += 32) {
    if (k0) __syncthreads();
#pragma unroll
    for (int c = 0; c < 2; ++c)
      gll16(Ab + (size_t)(c * 64 + srow) * K_ + k0 + slotg,
            smem + c * 4096 + wid * 1024);
#pragma unroll
    for (int c = 0; c < 2; ++c)
      gll16(Bb + (size_t)(c * 64 + srow) * K_ + k0 + slotg,
            smem + 8192 + c * 4096 + wid * 1024);
    __syncthreads();

#pragma unroll
    for (int ks = 0; ks < 2; ++ks) {
      const int sw = ks ? swk1 : swk0;
      const char* pa = smem + wr * 4096 + rA + sw;
      const char* pb = smem + 8192 + wc * 4096 + rA + sw;
      bf16x8 af[2], bf[2];
#pragma unroll
      for (int m = 0; m < 2; ++m) af[m] = *(const bf16x8*)(pa + m * 2048);
#pragma unroll
      for (int n = 0; n < 2; ++n) bf[n] = *(const bf16x8*)(pb + n * 2048);
#pragma unroll
      for (int m = 0; m < 2; ++m)
#pragma unroll
        for (int n = 0; n < 2; ++n)
          acc[m][n] = __builtin_amdgcn_mfma_f32_32x32x16_bf16(
              af[m], bf[n], acc[m][n], 0, 0, 0);
    }
  }

  const int crow0 = brow * 128 + wr * 64;
  const int ccol0 = bcol * 128 + wc * 64 + (lane & 31);
  const int rhalf = (lane >> 5) * 4;
  const float db0 = bias[ccol0];
  const float db1 = bias[ccol0 + 32];
#pragma unroll
  for (int m = 0; m < 2; ++m) {
#pragma unroll
    for (int reg = 0; reg < 16; ++reg) {
      const int row = crow0 + m * 32 + (reg & 3) + 8 * (reg >> 2) + rhalf;
      O[(size_t)row * DM + ccol0]      = acc[m][0][reg] + db0;
      O[(size_t)row * DM + ccol0 + 32] = acc[m][1][reg] + db1;
    }
  }
}

// ---------------------------------------------------------------------- launch
extern "C" void kernel_launch(void* const* d_in, const int* in_sizes, int n_in,
                              void* d_out, int out_size, void* d_ws, size_t ws_size,
                              hipStream_t stream) {
  const float* x     = (const float*)d_in[0];
  const float* tw    = (const float*)d_in[3];
  const float* sn    = (const float*)d_in[4];
  const float* pq    = (const float*)d_in[5];
  const float* gates = (const float*)d_in[6];
  const float* upw   = (const float*)d_in[7];
  const float* upb   = (const float*)d_in[8];
  const float* dnw   = (const float*)d_in[9];
  const float* dnb   = (const float*)d_in[10];
  float* out = (float*)d_out;

  char* p = (char*)d_ws;
  unsigned short* xb  = (unsigned short*)p; p += (size_t)R_ * DM * 2;
  unsigned short* uwb = (unsigned short*)p; p += (size_t)DFF * DM * 2;
  unsigned short* dwb = (unsigned short*)p; p += (size_t)DM * DFF * 2;
  unsigned short* H   = (unsigned short*)p; p += (size_t)R_ * DFF * 2;
  int*   pidx = (int*)p;   p += (size_t)R_ * 4 * sizeof(int);
  float* pwt  = (float*)p; p += (size_t)R_ * 4 * sizeof(float);
  float* vbuf = (float*)p; p += (size_t)R_ * DM * sizeof(float);

  cvt_bf16_kernel<<<(R_ * DM / 8) / 256, 256, 0, stream>>>(x, xb, R_ * DM / 8);
  cvt_bf16_kernel<<<(DFF * DM / 8) / 256, 256, 0, stream>>>(upw, uwb, DFF * DM / 8);
  cvt_bf16_kernel<<<(DM * DFF / 8) / 256, 256, 0, stream>>>(dnw, dwb, DM * DFF / 8);

  vcomp_kernel<<<R_, 256, 0, stream>>>(sn, tw, vbuf);
  score_kernel<<<R_ / 16, 256, 0, stream>>>(vbuf, pq, pidx, pwt);

  // gemm1: 32 brow x 32 bcol = 1024 blocks; gemm2: 64 brow x 8 bcol = 512
  gemm1_kernel<<<(R_ / 256) * (DFF / 128), 256, 0, stream>>>(
      xb, uwb, upb, pidx, pwt, gates, H);
  gemm2_kernel<<<(R_ / 128) * (DM / 128), 256, 0, stream>>>(
      H, dwb, dnb, out);
}

// Round 10
// 391.019 us; speedup vs baseline: 1.1435x; 1.1435x over previous
//
#include <hip/hip_runtime.h>
#include <hip/hip_bf16.h>
#include <math.h>

// Problem constants
#define R_   8192    // B*S rows
#define DM   1024    // d_model
#define DFF  4096    // d_ff
#define NP   64      // n_patterns
#define KN   8       // K neurons

typedef __bf16 bf16x8 __attribute__((ext_vector_type(8)));
typedef float  f32x4  __attribute__((ext_vector_type(4)));

__device__ __forceinline__ unsigned short f2bf(float f) {
  union { float f; unsigned u; } v; v.f = f;
  unsigned u = v.u;
  return (unsigned short)((u + 0x7FFFu + ((u >> 16) & 1u)) >> 16);
}

__device__ __forceinline__ float dot4(const float4 a, const float4 b) {
  return a.x * b.x + a.y * b.y + a.z * b.z + a.w * b.w;
}

__device__ __forceinline__ void fma4(float4& a, float w, const float4 s) {
  a.x += w * s.x; a.y += w * s.y; a.z += w * s.z; a.w += w * s.w;
}

// ---------------------------------------------------------------- f32 -> bf16
__global__ __launch_bounds__(256) void cvt_bf16_kernel(
    const float* __restrict__ in, unsigned short* __restrict__ out, int n8) {
  int i = blockIdx.x * 256 + threadIdx.x;
  if (i >= n8) return;
  const float4* p = (const float4*)in + (size_t)i * 2;
  float4 a = p[0], b = p[1];
  uint4 r;
  r.x = (unsigned)f2bf(a.x) | ((unsigned)f2bf(a.y) << 16);
  r.y = (unsigned)f2bf(a.z) | ((unsigned)f2bf(a.w) << 16);
  r.z = (unsigned)f2bf(b.x) | ((unsigned)f2bf(b.y) << 16);
  r.w = (unsigned)f2bf(b.z) | ((unsigned)f2bf(b.w) << 16);
  ((uint4*)out)[i] = r;
}

// ------------------------- fused v-materialize + pattern scores/topk/softmax
// Wave handles 4 rows. v[r] computed directly into regs (lane owns 16 dims):
// v = sum_k tw[k]*sn[r,k,:]; then 64-pattern dot loop + butterfly reduce;
// wave-parallel top-4 argmax + softmax.  Eliminates the vbuf round-trip.
__global__ __launch_bounds__(256, 2) void patt_kernel(
    const float* __restrict__ sn,    // [R_][8][1024]
    const float* __restrict__ tw,    // [R_][8]
    const float* __restrict__ pq,    // [64][1024]
    int*   __restrict__ out_idx,     // [R_][4]
    float* __restrict__ out_w)       // [R_][4]
{
  const int lane = threadIdx.x & 63;
  const int wave = threadIdx.x >> 6;
  const int pos0 = (blockIdx.x * 4 + wave) * 4;

  float4 vr[4][4];
#pragma unroll
  for (int p = 0; p < 4; ++p) {
    const int r = pos0 + p;
    const float* wp = tw + (size_t)r * KN;
    const float* base = sn + (size_t)r * (KN * DM) + lane * 16;
    float4 a0 = {0,0,0,0}, a1 = {0,0,0,0}, a2 = {0,0,0,0}, a3 = {0,0,0,0};
#pragma unroll
    for (int k = 0; k < KN; ++k) {
      const float wk = wp[k];
      const float4* s = (const float4*)(base + k * DM);
      fma4(a0, wk, s[0]); fma4(a1, wk, s[1]);
      fma4(a2, wk, s[2]); fma4(a3, wk, s[3]);
    }
    vr[p][0] = a0; vr[p][1] = a1; vr[p][2] = a2; vr[p][3] = a3;
  }

  float sreg[4];
#pragma unroll 1
  for (int pat = 0; pat < NP; ++pat) {
    const float4* q = (const float4*)(pq + pat * DM + lane * 16);
    const float4 q0 = q[0], q1 = q[1], q2 = q[2], q3 = q[3];
    float part[4];
#pragma unroll
    for (int p = 0; p < 4; ++p)
      part[p] = dot4(q0, vr[p][0]) + dot4(q1, vr[p][1]) +
                dot4(q2, vr[p][2]) + dot4(q3, vr[p][3]);
#pragma unroll
    for (int off = 32; off >= 1; off >>= 1) {
#pragma unroll
      for (int p = 0; p < 4; ++p)
        part[p] += __shfl_xor(part[p], off, 64);
    }
    if (lane == pat) {
#pragma unroll
      for (int p = 0; p < 4; ++p) sreg[p] = part[p] * 0.03125f; // /sqrt(1024)
    }
  }

#pragma unroll
  for (int p = 0; p < 4; ++p) {
    float cur = sreg[p];
    float m0, m1, m2, m3; int i0, i1, i2, i3;
#define ARGMAX_STEP(MV, MI)                                   \
    {                                                         \
      float bv = cur; int bi = lane;                          \
      _Pragma("unroll")                                       \
      for (int off = 32; off >= 1; off >>= 1) {               \
        float ov = __shfl_xor(bv, off, 64);                   \
        int   oi = __shfl_xor(bi, off, 64);                   \
        if (ov > bv || (ov == bv && oi < bi)) { bv = ov; bi = oi; } \
      }                                                       \
      MV = bv; MI = bi;                                       \
      if (lane == bi) cur = -3.0e38f;                         \
    }
    ARGMAX_STEP(m0, i0) ARGMAX_STEP(m1, i1) ARGMAX_STEP(m2, i2) ARGMAX_STEP(m3, i3)
#undef ARGMAX_STEP
    const float e1 = __expf(m1 - m0), e2 = __expf(m2 - m0), e3 = __expf(m3 - m0);
    const float inv = 1.f / (1.f + e1 + e2 + e3);
    if (lane < 4) {
      const int r = pos0 + p;
      const int myi = (lane == 0) ? i0 : (lane == 1) ? i1 : (lane == 2) ? i2 : i3;
      const float mye = (lane == 0) ? 1.f : (lane == 1) ? e1 : (lane == 2) ? e2 : e3;
      out_idx[r * 4 + lane] = myi;
      out_w[r * 4 + lane] = mye * inv;
    }
  }
}

// ------------------------------------------------------------ GEMM machinery
__device__ __forceinline__ void gll16(const void* g, void* l) {
  __builtin_amdgcn_global_load_lds(
      (const __attribute__((address_space(1))) unsigned int*)g,
      (__attribute__((address_space(3))) unsigned int*)l, 16, 0, 0);
}

#define LGKM0 asm volatile("s_waitcnt lgkmcnt(0)" ::: "memory")
#define VMC(N) asm volatile("s_waitcnt vmcnt(%0)" ::"i"(N) : "memory")

// Benched-best GEMM structure (R6 bench: 369us total).  ONLY change this
// round: block->tile mapping is now L2-aware.  Old chunking gave each XCD a
// working set (full B panel + streaming A) >> 4MB L2, so ~all gll16 missed
// L2 and were served by L3 at ~5 TB/s -- the measured 450 TF wall on six
// different schedules.  New mapping: XCD = bid&7; within an XCD, bcol-minor
// micro-groups so {B-group + current A-panel} ~ 1.5-2.5 MB, L2-resident.

// ---- GEMM1: H = gelu_gate(xb[8192][1024] @ uwb[4096][1024]^T)
// block-tile 256x128, ring-3 LDS (3 x 24KB), 2 phases/K-tile, NT=32.
__global__ __launch_bounds__(256, 2) void gemm1_kernel(
    const unsigned short* __restrict__ A,
    const unsigned short* __restrict__ Bm,
    const float* __restrict__ bias,
    const int*   __restrict__ pidx,
    const float* __restrict__ pwt,
    const float* __restrict__ gates,
    unsigned short* __restrict__ H)
{
  extern __shared__ char smem[];
  constexpr int K_ = 1024, NT = 32;
  const int tid = threadIdx.x, lane = tid & 63, wid = tid >> 6;
  const int wr = wid >> 1, wc = wid & 1;

  // L2-aware mapping: XCD x covers bcols [x*4, x*4+4) x all 32 brows;
  // inner order bcol-minor so 4 consecutive blocks share one A-panel.
  const int xcd = (int)blockIdx.x & 7, lid = (int)blockIdx.x >> 3;
  const int brow = lid >> 2, bcol = xcd * 4 + (lid & 3);

  const unsigned short* Ab = A  + (size_t)brow * 256 * K_;
  const unsigned short* Bb = Bm + (size_t)bcol * 128 * K_;

  // staging offsets (element units)
  const int aSrc = (wid * 16 + (lane >> 2)) * K_ +
                   (((lane & 3) ^ ((lane >> 2) & 3)) * 8);
  const int ldsSt = wid * 1024;
  // frag read offsets (bytes within region)
  const int laneRd = (lane & 15) * 64 + (((lane >> 4) ^ (lane & 3)) * 16);
  const int aRd = wr * 8192 + laneRd;            // + ph*4096 + m*1024
  const int bRd = 16384 + wc * 4096 + laneRd;    // + n*1024

  f32x4 acc[8][4];
#pragma unroll
  for (int m = 0; m < 8; ++m)
#pragma unroll
    for (int n = 0; n < 4; ++n) acc[m][n] = (f32x4){0.f, 0.f, 0.f, 0.f};

#define G1_STA(BO, PG) { _Pragma("unroll") for (int i_ = 0; i_ < 4; ++i_)     \
    gll16((PG) + i_ * 64 * K_ + aSrc, smem + (BO) + i_ * 4096 + ldsSt); }
#define G1_STB(BO, PG) { _Pragma("unroll") for (int i_ = 0; i_ < 2; ++i_)     \
    gll16((PG) + i_ * 64 * K_ + aSrc, smem + (BO) + 16384 + i_ * 4096 + ldsSt); }

  // prologue: A0 B0 A1 B1 B2 (14 loads); confirm A0,B0
  G1_STA(0, Ab)           G1_STB(0, Bb)
  G1_STA(24576, Ab + 32)  G1_STB(24576, Bb + 32)
  G1_STB(49152, Bb + 64)
  VMC(8);
  __builtin_amdgcn_s_barrier();

  int o0 = 0, o1 = 24576, o2 = 49152;
#pragma unroll 1
  for (int j = 0; j < NT; ++j) {
    bf16x8 a[4], b[4];
    // ---- ph0: A-mh0 + B frags; stage A(j+2)
    {
      const char* pa = smem + o0 + aRd;
      const char* pb = smem + o0 + bRd;
#pragma unroll
      for (int m = 0; m < 4; ++m) a[m] = *(const bf16x8*)(pa + m * 1024);
#pragma unroll
      for (int n = 0; n < 4; ++n) b[n] = *(const bf16x8*)(pb + n * 1024);
    }
    if (j < NT - 2) G1_STA(o2, Ab + (j + 2) * 32)
    LGKM0;
    __builtin_amdgcn_s_barrier();
    __builtin_amdgcn_s_setprio(1);
#pragma unroll
    for (int m = 0; m < 4; ++m)
#pragma unroll
      for (int n = 0; n < 4; ++n)
        acc[m][n] = __builtin_amdgcn_mfma_f32_16x16x32_bf16(a[m], b[n], acc[m][n], 0, 0, 0);
    __builtin_amdgcn_s_setprio(0);
    // ---- ph1: A-mh1 frags; stage B(j+3); counted vmcnt
    {
      const char* pa = smem + o0 + aRd + 4096;
#pragma unroll
      for (int m = 0; m < 4; ++m) a[m] = *(const bf16x8*)(pa + m * 1024);
    }
    if (j < NT - 3) G1_STB(o0, Bb + (j + 3) * 32)
    LGKM0;
    if (j < NT - 2) { VMC(6); } else { VMC(0); }
    __builtin_amdgcn_s_barrier();
    __builtin_amdgcn_s_setprio(1);
#pragma unroll
    for (int m = 0; m < 4; ++m)
#pragma unroll
      for (int n = 0; n < 4; ++n)
        acc[4 + m][n] = __builtin_amdgcn_mfma_f32_16x16x32_bf16(a[m], b[n], acc[4 + m][n], 0, 0, 0);
    __builtin_amdgcn_s_setprio(0);
    const int t = o0; o0 = o1; o1 = o2; o2 = t;
  }
#undef G1_STA
#undef G1_STB

  // epilogue: C/D layout col = lane&15, row = (lane>>4)*4 + j
  const int crow0 = brow * 256 + wr * 128;
  const int ccol0 = bcol * 128 + wc * 64 + (lane & 15);
  const int rsub  = (lane >> 4) * 4;
#pragma unroll
  for (int m = 0; m < 8; ++m) {
    const int rbase = crow0 + m * 16 + rsub;
    int   ia[4][4];
    float wa[4][4];
#pragma unroll
    for (int j = 0; j < 4; ++j) {
      const int4   iq = *(const int4*)(pidx + (size_t)(rbase + j) * 4);
      const float4 wq = *(const float4*)(pwt + (size_t)(rbase + j) * 4);
      ia[j][0] = iq.x; ia[j][1] = iq.y; ia[j][2] = iq.z; ia[j][3] = iq.w;
      wa[j][0] = wq.x; wa[j][1] = wq.y; wa[j][2] = wq.z; wa[j][3] = wq.w;
    }
#pragma unroll
    for (int n = 0; n < 4; ++n) {
      const int col = ccol0 + n * 16;
      const float ub = bias[col];
#pragma unroll
      for (int j = 0; j < 4; ++j) {
        float g = wa[j][0] * gates[(size_t)ia[j][0] * DFF + col]
                + wa[j][1] * gates[(size_t)ia[j][1] * DFF + col]
                + wa[j][2] * gates[(size_t)ia[j][2] * DFF + col]
                + wa[j][3] * gates[(size_t)ia[j][3] * DFF + col];
        const float u   = acc[m][n][j] + ub;
        const float val = u * (1.f / (1.f + __expf(-g)));
        const float h   = 0.5f * val * (1.f + erff(val * 0.70710678118654752f));
        H[(size_t)(rbase + j) * DFF + col] = f2bf(h);
      }
    }
  }
}

// ---- GEMM2: out = H[8192][4096] @ dwb[1024][4096]^T + dnb
// block-tile 128x128 (grid 512 -> 2 blocks/CU), ring-4 LDS (4 x 16KB),
// 1 phase/K-tile, NT=128, counted vmcnt(8).
__global__ __launch_bounds__(256, 2) void gemm2_kernel(
    const unsigned short* __restrict__ A,
    const unsigned short* __restrict__ Bm,
    const float* __restrict__ bias,
    float* __restrict__ O)
{
  extern __shared__ char smem[];
  constexpr int K_ = 4096, NT = 128;
  const int tid = threadIdx.x, lane = tid & 63, wid = tid >> 6;
  const int wr = wid >> 1, wc = wid & 1;

  // L2-aware mapping: XCD x covers brows [x*8, x*8+8) x all 8 bcols;
  // bcol-minor inner so 8 consecutive blocks share one A-panel; B (2MB)
  // stays L2-resident per XCD.
  const int xcd = (int)blockIdx.x & 7, lid = (int)blockIdx.x >> 3;
  const int brow = xcd * 8 + (lid >> 3), bcol = lid & 7;

  const unsigned short* Ab = A  + (size_t)brow * 128 * K_;
  const unsigned short* Bb = Bm + (size_t)bcol * 128 * K_;

  const int aSrc = (wid * 16 + (lane >> 2)) * K_ +
                   (((lane & 3) ^ ((lane >> 2) & 3)) * 8);
  const int ldsSt = wid * 1024;
  const int laneRd = (lane & 15) * 64 + (((lane >> 4) ^ (lane & 3)) * 16);
  const int aRd = wr * 4096 + laneRd;           // + m*1024
  const int bRd = 8192 + wc * 4096 + laneRd;    // + n*1024

  f32x4 acc[4][4];
#pragma unroll
  for (int m = 0; m < 4; ++m)
#pragma unroll
    for (int n = 0; n < 4; ++n) acc[m][n] = (f32x4){0.f, 0.f, 0.f, 0.f};

#define G2_ST(BO, PGA, PGB) {                                                 \
    _Pragma("unroll") for (int i_ = 0; i_ < 2; ++i_)                          \
      gll16((PGA) + i_ * 64 * K_ + aSrc, smem + (BO) + i_ * 4096 + ldsSt);    \
    _Pragma("unroll") for (int i_ = 0; i_ < 2; ++i_)                          \
      gll16((PGB) + i_ * 64 * K_ + aSrc, smem + (BO) + 8192 + i_ * 4096 + ldsSt); }

  // prologue: tiles 0,1,2 (12 loads); confirm tile 0
  G2_ST(0,     Ab,      Bb)
  G2_ST(16384, Ab + 32, Bb + 32)
  G2_ST(32768, Ab + 64, Bb + 64)
  VMC(8);
  __builtin_amdgcn_s_barrier();

  int o0 = 0, o1 = 16384, o2 = 32768, o3 = 49152;
#pragma unroll 1
  for (int j = 0; j < NT; ++j) {
    bf16x8 a[4], b[4];
    {
      const char* pa = smem + o0 + aRd;
      const char* pb = smem + o0 + bRd;
#pragma unroll
      for (int m = 0; m < 4; ++m) a[m] = *(const bf16x8*)(pa + m * 1024);
#pragma unroll
      for (int n = 0; n < 4; ++n) b[n] = *(const bf16x8*)(pb + n * 1024);
    }
    if (j < NT - 3) G2_ST(o3, Ab + (j + 3) * 32, Bb + (j + 3) * 32)
    LGKM0;
    if (j < NT - 3)      { VMC(8); }
    else if (j == NT - 3){ VMC(4); }
    else                 { VMC(0); }
    __builtin_amdgcn_s_barrier();
    __builtin_amdgcn_s_setprio(1);
#pragma unroll
    for (int m = 0; m < 4; ++m)
#pragma unroll
      for (int n = 0; n < 4; ++n)
        acc[m][n] = __builtin_amdgcn_mfma_f32_16x16x32_bf16(a[m], b[n], acc[m][n], 0, 0, 0);
    __builtin_amdgcn_s_setprio(0);
    const int t = o0; o0 = o1; o1 = o2; o2 = o3; o3 = t;
  }
#undef G2_ST

  const int crow0 = brow * 128 + wr * 64;
  const int ccol0 = bcol * 128 + wc * 64 + (lane & 15);
  const int rsub  = (lane >> 4) * 4;
#pragma unroll
  for (int m = 0; m < 4; ++m) {
    const int rbase = crow0 + m * 16 + rsub;
#pragma unroll
    for (int n = 0; n < 4; ++n) {
      const int col = ccol0 + n * 16;
      const float db = bias[col];
#pragma unroll
      for (int j = 0; j < 4; ++j)
        O[(size_t)(rbase + j) * DM + col] = acc[m][n][j] + db;
    }
  }
}

// ---------------------------------------------------------------------- launch
extern "C" void kernel_launch(void* const* d_in, const int* in_sizes, int n_in,
                              void* d_out, int out_size, void* d_ws, size_t ws_size,
                              hipStream_t stream) {
  const float* x     = (const float*)d_in[0];
  const float* tw    = (const float*)d_in[3];
  const float* sn    = (const float*)d_in[4];
  const float* pq    = (const float*)d_in[5];
  const float* gates = (const float*)d_in[6];
  const float* upw   = (const float*)d_in[7];
  const float* upb   = (const float*)d_in[8];
  const float* dnw   = (const float*)d_in[9];
  const float* dnb   = (const float*)d_in[10];
  float* out = (float*)d_out;

  char* p = (char*)d_ws;
  unsigned short* xb  = (unsigned short*)p; p += (size_t)R_ * DM * 2;
  unsigned short* uwb = (unsigned short*)p; p += (size_t)DFF * DM * 2;
  unsigned short* dwb = (unsigned short*)p; p += (size_t)DM * DFF * 2;
  unsigned short* H   = (unsigned short*)p; p += (size_t)R_ * DFF * 2;
  int*   pidx = (int*)p;   p += (size_t)R_ * 4 * sizeof(int);
  float* pwt  = (float*)p; p += (size_t)R_ * 4 * sizeof(float);

  cvt_bf16_kernel<<<(R_ * DM / 8) / 256, 256, 0, stream>>>(x, xb, R_ * DM / 8);
  cvt_bf16_kernel<<<(DFF * DM / 8) / 256, 256, 0, stream>>>(upw, uwb, DFF * DM / 8);
  cvt_bf16_kernel<<<(DM * DFF / 8) / 256, 256, 0, stream>>>(dnw, dwb, DM * DFF / 8);

  patt_kernel<<<R_ / 16, 256, 0, stream>>>(sn, tw, pq, pidx, pwt);

  hipFuncSetAttribute((const void*)gemm1_kernel,
                      hipFuncAttributeMaxDynamicSharedMemorySize, 73728);
  hipFuncSetAttribute((const void*)gemm2_kernel,
                      hipFuncAttributeMaxDynamicSharedMemorySize, 65536);

  // gemm1: 1024 blocks (8 XCD x 32 brow x 4 bcol); gemm2: 512 blocks
  gemm1_kernel<<<(R_ / 256) * (DFF / 128), 256, 73728, stream>>>(
      xb, uwb, upb, pidx, pwt, gates, H);
  gemm2_kernel<<<(R_ / 128) * (DM / 128), 256, 65536, stream>>>(
      H, dwb, dnb, out);
}

// Round 11
// 373.105 us; speedup vs baseline: 1.1984x; 1.0480x over previous
//
#include <hip/hip_runtime.h>
#include <hip/hip_bf16.h>
#include <math.h>

// Problem constants
#define R_   8192    // B*S rows
#define DM   1024    // d_model
#define DFF  4096    // d_ff
#define NP   64      // n_patterns
#define KN   8       // K neurons

typedef __bf16 bf16x8 __attribute__((ext_vector_type(8)));
typedef float  f32x4  __attribute__((ext_vector_type(4)));

__device__ __forceinline__ unsigned short f2bf(float f) {
  union { float f; unsigned u; } v; v.f = f;
  unsigned u = v.u;
  return (unsigned short)((u + 0x7FFFu + ((u >> 16) & 1u)) >> 16);
}

__device__ __forceinline__ float dot4(const float4 a, const float4 b) {
  return a.x * b.x + a.y * b.y + a.z * b.z + a.w * b.w;
}

__device__ __forceinline__ void fma4(float4& a, float w, const float4 s) {
  a.x += w * s.x; a.y += w * s.y; a.z += w * s.z; a.w += w * s.w;
}

// ---------------------------------------------------------------- f32 -> bf16
__global__ __launch_bounds__(256) void cvt_bf16_kernel(
    const float* __restrict__ in, unsigned short* __restrict__ out, int n8) {
  int i = blockIdx.x * 256 + threadIdx.x;
  if (i >= n8) return;
  const float4* p = (const float4*)in + (size_t)i * 2;
  float4 a = p[0], b = p[1];
  uint4 r;
  r.x = (unsigned)f2bf(a.x) | ((unsigned)f2bf(a.y) << 16);
  r.y = (unsigned)f2bf(a.z) | ((unsigned)f2bf(a.w) << 16);
  r.z = (unsigned)f2bf(b.x) | ((unsigned)f2bf(b.y) << 16);
  r.w = (unsigned)f2bf(b.z) | ((unsigned)f2bf(b.w) << 16);
  ((uint4*)out)[i] = r;
}

// -------------------------------------------------------------- v materialize
// v[r,d] = sum_k tw[r,k]*sn[r,k,d].  8192 blocks (one row each) = the
// latency-hiding lever for the 256MB sn stream (R2-proven ~50us).
__global__ __launch_bounds__(256) void vcomp_kernel(
    const float* __restrict__ sn,    // [R_][8][1024]
    const float* __restrict__ tw,    // [R_][8]
    float* __restrict__ v)           // [R_][1024]
{
  const int r = blockIdx.x;
  const int t = threadIdx.x;
  float w[KN];
#pragma unroll
  for (int k = 0; k < KN; ++k) w[k] = tw[(size_t)r * KN + k];
  const float* base = sn + (size_t)r * (KN * DM) + t * 4;
  float4 a = {0.f, 0.f, 0.f, 0.f};
#pragma unroll
  for (int k = 0; k < KN; ++k) fma4(a, w[k], *(const float4*)(base + k * DM));
  *(float4*)(v + (size_t)r * DM + t * 4) = a;
}

// ------------------------------------------------- pattern scores/topk/softmax
__global__ __launch_bounds__(256, 2) void score_kernel(
    const float* __restrict__ v,     // [R_][1024]
    const float* __restrict__ pq,    // [64][1024]
    int*   __restrict__ out_idx,     // [R_][4]
    float* __restrict__ out_w)       // [R_][4]
{
  const int lane = threadIdx.x & 63;
  const int wave = threadIdx.x >> 6;
  const int pos0 = (blockIdx.x * 4 + wave) * 4;

  float4 vr[4][4];
#pragma unroll
  for (int p = 0; p < 4; ++p) {
    const float4* s = (const float4*)(v + (size_t)(pos0 + p) * DM + lane * 16);
    vr[p][0] = s[0]; vr[p][1] = s[1]; vr[p][2] = s[2]; vr[p][3] = s[3];
  }

  float sreg[4];
#pragma unroll 1
  for (int pat = 0; pat < NP; ++pat) {
    const float4* q = (const float4*)(pq + pat * DM + lane * 16);
    const float4 q0 = q[0], q1 = q[1], q2 = q[2], q3 = q[3];
    float part[4];
#pragma unroll
    for (int p = 0; p < 4; ++p)
      part[p] = dot4(q0, vr[p][0]) + dot4(q1, vr[p][1]) +
                dot4(q2, vr[p][2]) + dot4(q3, vr[p][3]);
#pragma unroll
    for (int off = 32; off >= 1; off >>= 1) {
#pragma unroll
      for (int p = 0; p < 4; ++p)
        part[p] += __shfl_xor(part[p], off, 64);
    }
    if (lane == pat) {
#pragma unroll
      for (int p = 0; p < 4; ++p) sreg[p] = part[p] * 0.03125f; // /sqrt(1024)
    }
  }

#pragma unroll
  for (int p = 0; p < 4; ++p) {
    float cur = sreg[p];
    float m0, m1, m2, m3; int i0, i1, i2, i3;
#define ARGMAX_STEP(MV, MI)                                   \
    {                                                         \
      float bv = cur; int bi = lane;                          \
      _Pragma("unroll")                                       \
      for (int off = 32; off >= 1; off >>= 1) {               \
        float ov = __shfl_xor(bv, off, 64);                   \
        int   oi = __shfl_xor(bi, off, 64);                   \
        if (ov > bv || (ov == bv && oi < bi)) { bv = ov; bi = oi; } \
      }                                                       \
      MV = bv; MI = bi;                                       \
      if (lane == bi) cur = -3.0e38f;                         \
    }
    ARGMAX_STEP(m0, i0) ARGMAX_STEP(m1, i1) ARGMAX_STEP(m2, i2) ARGMAX_STEP(m3, i3)
#undef ARGMAX_STEP
    const float e1 = __expf(m1 - m0), e2 = __expf(m2 - m0), e3 = __expf(m3 - m0);
    const float inv = 1.f / (1.f + e1 + e2 + e3);
    if (lane < 4) {
      const int r = pos0 + p;
      const int myi = (lane == 0) ? i0 : (lane == 1) ? i1 : (lane == 2) ? i2 : i3;
      const float mye = (lane == 0) ? 1.f : (lane == 1) ? e1 : (lane == 2) ? e2 : e3;
      out_idx[r * 4 + lane] = myi;
      out_w[r * 4 + lane] = mye * inv;
    }
  }
}

// ------------------------------------------------------------ GEMM machinery
__device__ __forceinline__ void gll16(const void* g, void* l) {
  __builtin_amdgcn_global_load_lds(
      (const __attribute__((address_space(1))) unsigned int*)g,
      (__attribute__((address_space(3))) unsigned int*)l, 16, 0, 0);
}

#define LGKM0 asm volatile("s_waitcnt lgkmcnt(0)" ::: "memory")
#define VMC(N) asm volatile("s_waitcnt vmcnt(%0)" ::"i"(N) : "memory")

// R10-benched GEMMs (L2-aware XCD mapping; gemm1+gemm2 ~200us combined).
// Mapping rationale: XCD = bid&7; within an XCD, bcol-minor micro-groups so
// {B-group + current A-panel} fits the 4MB per-XCD L2; the 450TF L3-BW wall
// (six schedule variants, R2-R8) was lifted by this mapping alone.

// ---- GEMM1: H = gelu_gate(xb[8192][1024] @ uwb[4096][1024]^T)
// block-tile 256x128, ring-3 LDS (3 x 24KB), 2 phases/K-tile, NT=32.
__global__ __launch_bounds__(256, 2) void gemm1_kernel(
    const unsigned short* __restrict__ A,
    const unsigned short* __restrict__ Bm,
    const float* __restrict__ bias,
    const int*   __restrict__ pidx,
    const float* __restrict__ pwt,
    const float* __restrict__ gates,
    unsigned short* __restrict__ H)
{
  extern __shared__ char smem[];
  constexpr int K_ = 1024, NT = 32;
  const int tid = threadIdx.x, lane = tid & 63, wid = tid >> 6;
  const int wr = wid >> 1, wc = wid & 1;

  // L2-aware mapping: XCD x covers bcols [x*4, x*4+4) x all 32 brows;
  // inner order bcol-minor so 4 consecutive blocks share one A-panel.
  const int xcd = (int)blockIdx.x & 7, lid = (int)blockIdx.x >> 3;
  const int brow = lid >> 2, bcol = xcd * 4 + (lid & 3);

  const unsigned short* Ab = A  + (size_t)brow * 256 * K_;
  const unsigned short* Bb = Bm + (size_t)bcol * 128 * K_;

  // staging offsets (element units)
  const int aSrc = (wid * 16 + (lane >> 2)) * K_ +
                   (((lane & 3) ^ ((lane >> 2) & 3)) * 8);
  const int ldsSt = wid * 1024;
  // frag read offsets (bytes within region)
  const int laneRd = (lane & 15) * 64 + (((lane >> 4) ^ (lane & 3)) * 16);
  const int aRd = wr * 8192 + laneRd;            // + ph*4096 + m*1024
  const int bRd = 16384 + wc * 4096 + laneRd;    // + n*1024

  f32x4 acc[8][4];
#pragma unroll
  for (int m = 0; m < 8; ++m)
#pragma unroll
    for (int n = 0; n < 4; ++n) acc[m][n] = (f32x4){0.f, 0.f, 0.f, 0.f};

#define G1_STA(BO, PG) { _Pragma("unroll") for (int i_ = 0; i_ < 4; ++i_)     \
    gll16((PG) + i_ * 64 * K_ + aSrc, smem + (BO) + i_ * 4096 + ldsSt); }
#define G1_STB(BO, PG) { _Pragma("unroll") for (int i_ = 0; i_ < 2; ++i_)     \
    gll16((PG) + i_ * 64 * K_ + aSrc, smem + (BO) + 16384 + i_ * 4096 + ldsSt); }

  // prologue: A0 B0 A1 B1 B2 (14 loads); confirm A0,B0
  G1_STA(0, Ab)           G1_STB(0, Bb)
  G1_STA(24576, Ab + 32)  G1_STB(24576, Bb + 32)
  G1_STB(49152, Bb + 64)
  VMC(8);
  __builtin_amdgcn_s_barrier();

  int o0 = 0, o1 = 24576, o2 = 49152;
#pragma unroll 1
  for (int j = 0; j < NT; ++j) {
    bf16x8 a[4], b[4];
    // ---- ph0: A-mh0 + B frags; stage A(j+2)
    {
      const char* pa = smem + o0 + aRd;
      const char* pb = smem + o0 + bRd;
#pragma unroll
      for (int m = 0; m < 4; ++m) a[m] = *(const bf16x8*)(pa + m * 1024);
#pragma unroll
      for (int n = 0; n < 4; ++n) b[n] = *(const bf16x8*)(pb + n * 1024);
    }
    if (j < NT - 2) G1_STA(o2, Ab + (j + 2) * 32)
    LGKM0;
    __builtin_amdgcn_s_barrier();
    __builtin_amdgcn_s_setprio(1);
#pragma unroll
    for (int m = 0; m < 4; ++m)
#pragma unroll
      for (int n = 0; n < 4; ++n)
        acc[m][n] = __builtin_amdgcn_mfma_f32_16x16x32_bf16(a[m], b[n], acc[m][n], 0, 0, 0);
    __builtin_amdgcn_s_setprio(0);
    // ---- ph1: A-mh1 frags; stage B(j+3); counted vmcnt
    {
      const char* pa = smem + o0 + aRd + 4096;
#pragma unroll
      for (int m = 0; m < 4; ++m) a[m] = *(const bf16x8*)(pa + m * 1024);
    }
    if (j < NT - 3) G1_STB(o0, Bb + (j + 3) * 32)
    LGKM0;
    if (j < NT - 2) { VMC(6); } else { VMC(0); }
    __builtin_amdgcn_s_barrier();
    __builtin_amdgcn_s_setprio(1);
#pragma unroll
    for (int m = 0; m < 4; ++m)
#pragma unroll
      for (int n = 0; n < 4; ++n)
        acc[4 + m][n] = __builtin_amdgcn_mfma_f32_16x16x32_bf16(a[m], b[n], acc[4 + m][n], 0, 0, 0);
    __builtin_amdgcn_s_setprio(0);
    const int t = o0; o0 = o1; o1 = o2; o2 = t;
  }
#undef G1_STA
#undef G1_STB

  // epilogue: C/D layout col = lane&15, row = (lane>>4)*4 + j
  const int crow0 = brow * 256 + wr * 128;
  const int ccol0 = bcol * 128 + wc * 64 + (lane & 15);
  const int rsub  = (lane >> 4) * 4;
#pragma unroll
  for (int m = 0; m < 8; ++m) {
    const int rbase = crow0 + m * 16 + rsub;
    int   ia[4][4];
    float wa[4][4];
#pragma unroll
    for (int j = 0; j < 4; ++j) {
      const int4   iq = *(const int4*)(pidx + (size_t)(rbase + j) * 4);
      const float4 wq = *(const float4*)(pwt + (size_t)(rbase + j) * 4);
      ia[j][0] = iq.x; ia[j][1] = iq.y; ia[j][2] = iq.z; ia[j][3] = iq.w;
      wa[j][0] = wq.x; wa[j][1] = wq.y; wa[j][2] = wq.z; wa[j][3] = wq.w;
    }
#pragma unroll
    for (int n = 0; n < 4; ++n) {
      const int col = ccol0 + n * 16;
      const float ub = bias[col];
#pragma unroll
      for (int j = 0; j < 4; ++j) {
        float g = wa[j][0] * gates[(size_t)ia[j][0] * DFF + col]
                + wa[j][1] * gates[(size_t)ia[j][1] * DFF + col]
                + wa[j][2] * gates[(size_t)ia[j][2] * DFF + col]
                + wa[j][3] * gates[(size_t)ia[j][3] * DFF + col];
        const float u   = acc[m][n][j] + ub;
        const float val = u * (1.f / (1.f + __expf(-g)));
        const float h   = 0.5f * val * (1.f + erff(val * 0.70710678118654752f));
        H[(size_t)(rbase + j) * DFF + col] = f2bf(h);
      }
    }
  }
}

// ---- GEMM2: out = H[8192][4096] @ dwb[1024][4096]^T + dnb
// block-tile 128x128 (grid 512 -> 2 blocks/CU), ring-4 LDS (4 x 16KB),
// 1 phase/K-tile, NT=128, counted vmcnt(8).
__global__ __launch_bounds__(256, 2) void gemm2_kernel(
    const unsigned short* __restrict__ A,
    const unsigned short* __restrict__ Bm,
    const float* __restrict__ bias,
    float* __restrict__ O)
{
  extern __shared__ char smem[];
  constexpr int K_ = 4096, NT = 128;
  const int tid = threadIdx.x, lane = tid & 63, wid = tid >> 6;
  const int wr = wid >> 1, wc = wid & 1;

  // L2-aware mapping: XCD x covers brows [x*8, x*8+8) x all 8 bcols;
  // bcol-minor inner so 8 consecutive blocks share one A-panel; B (2MB)
  // stays L2-resident per XCD.
  const int xcd = (int)blockIdx.x & 7, lid = (int)blockIdx.x >> 3;
  const int brow = xcd * 8 + (lid >> 3), bcol = lid & 7;

  const unsigned short* Ab = A  + (size_t)brow * 128 * K_;
  const unsigned short* Bb = Bm + (size_t)bcol * 128 * K_;

  const int aSrc = (wid * 16 + (lane >> 2)) * K_ +
                   (((lane & 3) ^ ((lane >> 2) & 3)) * 8);
  const int ldsSt = wid * 1024;
  const int laneRd = (lane & 15) * 64 + (((lane >> 4) ^ (lane & 3)) * 16);
  const int aRd = wr * 4096 + laneRd;           // + m*1024
  const int bRd = 8192 + wc * 4096 + laneRd;    // + n*1024

  f32x4 acc[4][4];
#pragma unroll
  for (int m = 0; m < 4; ++m)
#pragma unroll
    for (int n = 0; n < 4; ++n) acc[m][n] = (f32x4){0.f, 0.f, 0.f, 0.f};

#define G2_ST(BO, PGA, PGB) {                                                 \
    _Pragma("unroll") for (int i_ = 0; i_ < 2; ++i_)                          \
      gll16((PGA) + i_ * 64 * K_ + aSrc, smem + (BO) + i_ * 4096 + ldsSt);    \
    _Pragma("unroll") for (int i_ = 0; i_ < 2; ++i_)                          \
      gll16((PGB) + i_ * 64 * K_ + aSrc, smem + (BO) + 8192 + i_ * 4096 + ldsSt); }

  // prologue: tiles 0,1,2 (12 loads); confirm tile 0
  G2_ST(0,     Ab,      Bb)
  G2_ST(16384, Ab + 32, Bb + 32)
  G2_ST(32768, Ab + 64, Bb + 64)
  VMC(8);
  __builtin_amdgcn_s_barrier();

  int o0 = 0, o1 = 16384, o2 = 32768, o3 = 49152;
#pragma unroll 1
  for (int j = 0; j < NT; ++j) {
    bf16x8 a[4], b[4];
    {
      const char* pa = smem + o0 + aRd;
      const char* pb = smem + o0 + bRd;
#pragma unroll
      for (int m = 0; m < 4; ++m) a[m] = *(const bf16x8*)(pa + m * 1024);
#pragma unroll
      for (int n = 0; n < 4; ++n) b[n] = *(const bf16x8*)(pb + n * 1024);
    }
    if (j < NT - 3) G2_ST(o3, Ab + (j + 3) * 32, Bb + (j + 3) * 32)
    LGKM0;
    if (j < NT - 3)      { VMC(8); }
    else if (j == NT - 3){ VMC(4); }
    else                 { VMC(0); }
    __builtin_amdgcn_s_barrier();
    __builtin_amdgcn_s_setprio(1);
#pragma unroll
    for (int m = 0; m < 4; ++m)
#pragma unroll
      for (int n = 0; n < 4; ++n)
        acc[m][n] = __builtin_amdgcn_mfma_f32_16x16x32_bf16(a[m], b[n], acc[m][n], 0, 0, 0);
    __builtin_amdgcn_s_setprio(0);
    const int t = o0; o0 = o1; o1 = o2; o2 = o3; o3 = t;
  }
#undef G2_ST

  const int crow0 = brow * 128 + wr * 64;
  const int ccol0 = bcol * 128 + wc * 64 + (lane & 15);
  const int rsub  = (lane >> 4) * 4;
#pragma unroll
  for (int m = 0; m < 4; ++m) {
    const int rbase = crow0 + m * 16 + rsub;
#pragma unroll
    for (int n = 0; n < 4; ++n) {
      const int col = ccol0 + n * 16;
      const float db = bias[col];
#pragma unroll
      for (int j = 0; j < 4; ++j)
        O[(size_t)(rbase + j) * DM + col] = acc[m][n][j] + db;
    }
  }
}

// ---------------------------------------------------------------------- launch
extern "C" void kernel_launch(void* const* d_in, const int* in_sizes, int n_in,
                              void* d_out, int out_size, void* d_ws, size_t ws_size,
                              hipStream_t stream) {
  const float* x     = (const float*)d_in[0];
  const float* tw    = (const float*)d_in[3];
  const float* sn    = (const float*)d_in[4];
  const float* pq    = (const float*)d_in[5];
  const float* gates = (const float*)d_in[6];
  const float* upw   = (const float*)d_in[7];
  const float* upb   = (const float*)d_in[8];
  const float* dnw   = (const float*)d_in[9];
  const float* dnb   = (const float*)d_in[10];
  float* out = (float*)d_out;

  char* p = (char*)d_ws;
  unsigned short* xb  = (unsigned short*)p; p += (size_t)R_ * DM * 2;
  unsigned short* uwb = (unsigned short*)p; p += (size_t)DFF * DM * 2;
  unsigned short* dwb = (unsigned short*)p; p += (size_t)DM * DFF * 2;
  unsigned short* H   = (unsigned short*)p; p += (size_t)R_ * DFF * 2;
  int*   pidx = (int*)p;   p += (size_t)R_ * 4 * sizeof(int);
  float* pwt  = (float*)p; p += (size_t)R_ * 4 * sizeof(float);
  float* vbuf = (float*)p; p += (size_t)R_ * DM * sizeof(float);

  cvt_bf16_kernel<<<(R_ * DM / 8) / 256, 256, 0, stream>>>(x, xb, R_ * DM / 8);
  cvt_bf16_kernel<<<(DFF * DM / 8) / 256, 256, 0, stream>>>(upw, uwb, DFF * DM / 8);
  cvt_bf16_kernel<<<(DM * DFF / 8) / 256, 256, 0, stream>>>(dnw, dwb, DM * DFF / 8);

  vcomp_kernel<<<R_, 256, 0, stream>>>(sn, tw, vbuf);
  score_kernel<<<R_ / 16, 256, 0, stream>>>(vbuf, pq, pidx, pwt);

  hipFuncSetAttribute((const void*)gemm1_kernel,
                      hipFuncAttributeMaxDynamicSharedMemorySize, 73728);
  hipFuncSetAttribute((const void*)gemm2_kernel,
                      hipFuncAttributeMaxDynamicSharedMemorySize, 65536);

  // gemm1: 1024 blocks (8 XCD x 32 brow x 4 bcol); gemm2: 512 blocks
  gemm1_kernel<<<(R_ / 256) * (DFF / 128), 256, 73728, stream>>>(
      xb, uwb, upb, pidx, pwt, gates, H);
  gemm2_kernel<<<(R_ / 128) * (DM / 128), 256, 65536, stream>>>(
      H, dwb, dnb, out);
}